// Round 6
// baseline (501.193 us; speedup 1.0000x reference)
//
#include <hip/hip_runtime.h>
#include <hip/hip_bf16.h>
#include <math.h>

using short8 = __attribute__((ext_vector_type(8))) short;
using f32x4  = __attribute__((ext_vector_type(4))) float;

#define MFMA_B16(A,B,C) __builtin_amdgcn_mfma_f32_16x16x32_bf16((A),(B),(C),0,0,0)

// ---------------- LDS layout (bytes) ----------------
// Two windows per block. Per window: aln [49][392]u16 (spill reads land in
// later regions: garbage rows only feed discarded C rows / masked scores);
// pool: q2/k2 [49][72], vT2 [64][72] (zero-init, token cols>=49 stay 0),
// oh [64][72]. MLP: hid double-buffer 2x[64][136] aliases the pool.
#define ALN_STR 392
#define ALN_SZ  38416
#define POOL    76832          // = 2*ALN_SZ
#define PS      34816          // per-window pool stride (= 2 hid buffers)
#define QK_STR  72
#define VT_STR  72
#define OH_STR  72
#define HID_STR 136
#define SMEM_BYTES 146464      // 76832 + 2*34816 <= 160 KiB

__device__ __forceinline__ unsigned short f2bfu(float x) {   // RNE f32->bf16
  unsigned u = __float_as_uint(x);
  return (unsigned short)((u + 0x7fffu + ((u >> 16) & 1u)) >> 16);
}
__device__ __forceinline__ unsigned pk2(float a, float b) {
  return (unsigned)f2bfu(a) | ((unsigned)f2bfu(b) << 16);
}

// B-operand load. WBF: packed fragment layout [tile][kchunk][lane][8] bf16 ->
// one coalesced 16B/lane read. !WBF: gather from f32 row-major + convert.
template<bool WBF>
__device__ __forceinline__ short8 loadW(const void* base, int tile, int K8, int kcb,
                                        int l, int row, int ldk, int k0) {
  if constexpr (WBF) {
    return *(const short8*)((const unsigned short*)base +
                            (((size_t)(tile * K8 + kcb)) << 7) + l * 8);
  } else {
    const float* p = (const float*)base + (size_t)row * ldk + k0;
    float4 x = *(const float4*)p;
    float4 y = *(const float4*)(p + 4);
    short8 r;
    r[0]=(short)f2bfu(x.x); r[1]=(short)f2bfu(x.y); r[2]=(short)f2bfu(x.z); r[3]=(short)f2bfu(x.w);
    r[4]=(short)f2bfu(y.x); r[5]=(short)f2bfu(y.y); r[6]=(short)f2bfu(y.z); r[7]=(short)f2bfu(y.w);
    return r;
  }
}

// Repack f32 [rows][K] -> bf16 fragment order [tile][kc][r16][8].
__global__ void cvt_pack(const float* __restrict__ src, unsigned short* __restrict__ dst,
                         int K, int n) {
  int K8 = K >> 3;
  int i = blockIdx.x * blockDim.x + threadIdx.x;
  if (i >= n) return;
  int e = i & 7;
  int idx = i >> 3;
  int r = idx & 15; idx >>= 4;
  int kc = idx % K8, ci = idx / K8;
  dst[i] = f2bfu(src[(size_t)(ci * 16 + r) * K + kc * 8 + e]);
}

template<bool WBF>
__global__ __launch_bounds__(1024, 4)
void swin_mfma(const float* __restrict__ tokens,
               const void* __restrict__ ipw,  const float* __restrict__ ipb,
               const void* __restrict__ outw, const float* __restrict__ outb,
               const float* __restrict__ ln1g, const float* __restrict__ ln1b,
               const void* __restrict__ w1,   const float* __restrict__ b1,
               const void* __restrict__ w2,   const float* __restrict__ b2,
               const float* __restrict__ ln2g, const float* __restrict__ ln2b,
               float* __restrict__ out)
{
  extern __shared__ char smem[];
  const int tid = threadIdx.x;
  const int win = tid >> 9;            // which of the 2 windows this thread serves
  const int wv  = (tid >> 6) & 7;      // wave id within window group (0..7)
  const int l   = tid & 63;
  const int cl  = l & 15, kg = l >> 4;
  const int wid = blockIdx.x * 2 + win;
  const int iw = wid & 7, ih = (wid >> 3) & 7, bt = wid >> 6;

  unsigned short* aln = (unsigned short*)(smem + win * ALN_SZ);
  char* pool = smem + POOL + win * PS;
  unsigned short* q2   = (unsigned short*)(pool);
  unsigned short* k2   = (unsigned short*)(pool + 7056);
  unsigned short* vT2  = (unsigned short*)(pool + 14112);
  unsigned short* oh   = (unsigned short*)(pool + 23328);
  unsigned short* hid0 = (unsigned short*)(pool);
  unsigned short* hid1 = (unsigned short*)(pool + 17408);

  auto gidx = [&](int r, int c) -> size_t {
    int wi = r / 7, wj = r - wi * 7;
    return ((size_t)bt * 3136 + (size_t)((ih*7 + wi) * 56 + iw*7 + wj)) * 384 + c;
  };

  auto ln_pass = [&](const float* src, const float* gw, const float* gb) {
    int row = (tid >> 3) & 63, lj = tid & 7;   // (tid>>3)>>6 == win: consistent
    if (row < 49) {
      size_t base = gidx(row, 0);
      float4 xv[12];
      float sx = 0.f, sxx = 0.f;
      #pragma unroll
      for (int k = 0; k < 12; ++k) {
        xv[k] = *(const float4*)&src[base + (lj + 8*k) * 4];
        sx  += xv[k].x + xv[k].y + xv[k].z + xv[k].w;
        sxx += xv[k].x*xv[k].x + xv[k].y*xv[k].y + xv[k].z*xv[k].z + xv[k].w*xv[k].w;
      }
      #pragma unroll
      for (int d = 1; d < 8; d <<= 1) { sx += __shfl_xor(sx, d, 8); sxx += __shfl_xor(sxx, d, 8); }
      float mean = sx * (1.f/384.f);
      float rs = rsqrtf(sxx * (1.f/384.f) - mean*mean + 1e-5f);
      unsigned short* arow = aln + row * ALN_STR;
      #pragma unroll
      for (int k = 0; k < 12; ++k) {
        int c = (lj + 8*k) * 4;
        float4 gv = *(const float4*)&gw[c];
        float4 bv = *(const float4*)&gb[c];
        unsigned u0 = pk2((xv[k].x-mean)*rs*gv.x + bv.x, (xv[k].y-mean)*rs*gv.y + bv.y);
        unsigned u1 = pk2((xv[k].z-mean)*rs*gv.z + bv.z, (xv[k].w-mean)*rs*gv.w + bv.w);
        *(uint2*)&arow[c] = make_uint2(u0, u1);
      }
    }
  };

  const int ri0 = wv & 3, chalf = wv >> 2;
  const int arow0 = (cl + 16 * ri0) * ALN_STR;

  // QKV for head pair pr: writes q2/k2/vT2 (rows<49 only). B loads pipelined.
  auto qkv = [&](int pr) {
    #pragma unroll
    for (int half = 0; half < 2; ++half) {
      int tilea[3], growa[3], parta[3], wta[3];
      #pragma unroll
      for (int j = 0; j < 3; ++j) {
        int ci = chalf + 2 * (half * 3 + j);
        parta[j] = ci >> 2; wta[j] = ci & 3;
        tilea[j] = parta[j] * 24 + pr * 4 + wta[j];
        growa[j] = parta[j] * 384 + pr * 64 + wta[j] * 16 + cl;
      }
      f32x4 d0{0,0,0,0}, d1{0,0,0,0}, d2{0,0,0,0};
      short8 a_c  = *(const short8*)&aln[arow0 + kg*8];
      short8 b0_c = loadW<WBF>(ipw, tilea[0], 48, 0, l, growa[0], 384, kg*8);
      short8 b1_c = loadW<WBF>(ipw, tilea[1], 48, 0, l, growa[1], 384, kg*8);
      short8 b2_c = loadW<WBF>(ipw, tilea[2], 48, 0, l, growa[2], 384, kg*8);
      #pragma unroll
      for (int kt = 0; kt < 12; ++kt) {
        short8 a_n, b0_n, b1_n, b2_n;
        if (kt < 11) {
          int k1 = (kt+1)*32 + kg*8;
          a_n  = *(const short8*)&aln[arow0 + k1];
          b0_n = loadW<WBF>(ipw, tilea[0], 48, (kt+1)*4, l, growa[0], 384, k1);
          b1_n = loadW<WBF>(ipw, tilea[1], 48, (kt+1)*4, l, growa[1], 384, k1);
          b2_n = loadW<WBF>(ipw, tilea[2], 48, (kt+1)*4, l, growa[2], 384, k1);
        }
        d0 = MFMA_B16(a_c, b0_c, d0);
        d1 = MFMA_B16(a_c, b1_c, d1);
        d2 = MFMA_B16(a_c, b2_c, d2);
        a_c = a_n; b0_c = b0_n; b1_c = b1_n; b2_c = b2_n;
      }
      #pragma unroll
      for (int j = 0; j < 3; ++j) {
        f32x4 dd = (j == 0) ? d0 : (j == 1) ? d1 : d2;
        int within = wta[j] * 16 + cl;
        float bias = ipb[growa[j]];
        float scl = (parta[j] == 0) ? 0.17677669529663687f : 1.f;
        #pragma unroll
        for (int rg = 0; rg < 4; ++rg) {
          int row = kg * 4 + rg + 16 * ri0;
          if (row < 49) {
            unsigned short bv = f2bfu((dd[rg] + bias) * scl);
            if      (parta[j] == 0) q2[row * QK_STR + within] = bv;
            else if (parta[j] == 1) k2[row * QK_STR + within] = bv;
            else                    vT2[within * VT_STR + row] = bv;
          }
        }
      }
    }
  };

  // ---- init: zero vT2 pad (token cols >=49 must stay 0), LN1 ----
  for (int i = (tid & 511); i < (64*VT_STR)/2; i += 512)
    ((unsigned*)(pool + 14112))[i] = 0u;
  ln_pass(tokens, ln1g, ln1b);
  __syncthreads();

  f32x4 opacc[3][4];
  #pragma unroll
  for (int a = 0; a < 3; ++a)
    #pragma unroll
    for (int b = 0; b < 4; ++b) opacc[a][b] = f32x4{0.f,0.f,0.f,0.f};

  qkv(0);
  __syncthreads();

  const int hl = wv & 1, qci = wv >> 1;   // wave's (head-within-pair, q col-tile)

  for (int pr = 0; pr < 6; ++pr) {
    // ---- P_a: scores (swapped: mfma(K,Q)) + in-register softmax + PV ----
    {
      short8 bq = *(const short8*)&q2[(16*qci + cl) * QK_STR + hl*32 + kg*8];
      f32x4 dsc[4];
      #pragma unroll
      for (int kri = 0; kri < 4; ++kri) {
        short8 ak = *(const short8*)&k2[(16*kri + cl) * QK_STR + hl*32 + kg*8];
        f32x4 z{0.f,0.f,0.f,0.f};
        dsc[kri] = MFMA_B16(ak, bq, z);
      }
      // lane (cl,kg) holds scores(k=16kri+4kg+r, q=16qci+cl); mask k>=49
      float ev[4][4];
      float mx = -1e30f;
      #pragma unroll
      for (int kri = 0; kri < 4; ++kri)
        #pragma unroll
        for (int r = 0; r < 4; ++r) {
          int kidx = 16*kri + 4*kg + r;
          float v = (kidx < 49) ? dsc[kri][r] : -1e30f;
          ev[kri][r] = v;
          mx = fmaxf(mx, v);
        }
      mx = fmaxf(mx, __shfl_xor(mx, 16));
      mx = fmaxf(mx, __shfl_xor(mx, 32));
      float sum = 0.f;
      #pragma unroll
      for (int kri = 0; kri < 4; ++kri)
        #pragma unroll
        for (int r = 0; r < 4; ++r) {
          float e = __expf(ev[kri][r] - mx);
          ev[kri][r] = e; sum += e;
        }
      sum += __shfl_xor(sum, 16);
      sum += __shfl_xor(sum, 32);
      float inv = 1.f / sum;
      unsigned pk[4][2];
      #pragma unroll
      for (int kri = 0; kri < 4; ++kri) {
        pk[kri][0] = pk2(ev[kri][0]*inv, ev[kri][1]*inv);
        pk[kri][1] = pk2(ev[kri][2]*inv, ev[kri][3]*inv);
      }
      // PV (swapped: mfma(vT, P)) -> oh^T; P B-frags built by shuffles
      f32x4 dot0{0.f,0.f,0.f,0.f}, dot1{0.f,0.f,0.f,0.f};
      const int sA = cl + 32 * (kg & 1);
      const bool hi = (kg >> 1) & 1;
      #pragma unroll
      for (int kt = 0; kt < 2; ++kt) {
        unsigned x0 = (unsigned)__shfl((int)pk[2*kt][0],   sA);
        unsigned x1 = (unsigned)__shfl((int)pk[2*kt][1],   sA);
        unsigned x2 = (unsigned)__shfl((int)pk[2*kt][0],   sA + 16);
        unsigned x3 = (unsigned)__shfl((int)pk[2*kt][1],   sA + 16);
        unsigned y0 = (unsigned)__shfl((int)pk[2*kt+1][0], sA);
        unsigned y1 = (unsigned)__shfl((int)pk[2*kt+1][1], sA);
        unsigned y2 = (unsigned)__shfl((int)pk[2*kt+1][0], sA + 16);
        unsigned y3 = (unsigned)__shfl((int)pk[2*kt+1][1], sA + 16);
        uint4 bu = make_uint4(hi ? y0 : x0, hi ? y1 : x1, hi ? y2 : x2, hi ? y3 : x3);
        short8 bfrag = *(short8*)&bu;
        short8 a0 = *(const short8*)&vT2[(hl*32 +  0 + cl) * VT_STR + kt*32 + kg*8];
        short8 a1 = *(const short8*)&vT2[(hl*32 + 16 + cl) * VT_STR + kt*32 + kg*8];
        dot0 = MFMA_B16(a0, bfrag, dot0);
        dot1 = MFMA_B16(a1, bfrag, dot1);
      }
      int q = 16*qci + cl;
      if (q < 49) {
        int base = q * OH_STR + hl*32 + kg*4;
        *(unsigned*)&oh[base     ] = pk2(dot0[0], dot0[1]);
        *(unsigned*)&oh[base +  2] = pk2(dot0[2], dot0[3]);
        *(unsigned*)&oh[base + 16] = pk2(dot1[0], dot1[1]);
        *(unsigned*)&oh[base + 18] = pk2(dot1[2], dot1[3]);
      }
    }
    __syncthreads();

    // ---- P_b: out-proj(pr) (K=64, both heads) + QKV(pr+1) ----
    {
      short8 ao[4][2];
      #pragma unroll
      for (int ri = 0; ri < 4; ++ri)
        #pragma unroll
        for (int kt = 0; kt < 2; ++kt)
          ao[ri][kt] = *(const short8*)&oh[(cl + 16*ri) * OH_STR + kt*32 + kg*8];
      #pragma unroll
      for (int cii = 0; cii < 3; ++cii) {
        #pragma unroll
        for (int kt = 0; kt < 2; ++kt) {
          short8 bw = loadW<WBF>(outw, wv*3 + cii, 48, pr*8 + kt*4, l,
                                 (wv*3 + cii)*16 + cl, 384, pr*64 + kt*32 + kg*8);
          opacc[cii][0] = MFMA_B16(ao[0][kt], bw, opacc[cii][0]);
          opacc[cii][1] = MFMA_B16(ao[1][kt], bw, opacc[cii][1]);
          opacc[cii][2] = MFMA_B16(ao[2][kt], bw, opacc[cii][2]);
          opacc[cii][3] = MFMA_B16(ao[3][kt], bw, opacc[cii][3]);
        }
      }
      if (pr < 5) qkv(pr + 1);
    }
    __syncthreads();
  }

  // ---- win = tokens + attn + out_b -> out ----
  #pragma unroll
  for (int cii = 0; cii < 3; ++cii) {
    int col = (wv*3 + cii) * 16 + cl;
    float ob = outb[col];
    #pragma unroll
    for (int ri = 0; ri < 4; ++ri) {
      #pragma unroll
      for (int rg = 0; rg < 4; ++rg) {
        int row = kg*4 + rg + 16*ri;
        if (row < 49) {
          size_t g = gidx(row, col);
          out[g] = tokens[g] + opacc[cii][ri][rg] + ob;
        }
      }
    }
  }
  __syncthreads();

  // ---- LN2 ----
  ln_pass(out, ln2g, ln2b);
  __syncthreads();

  // ---- MLP: double-buffered hid, MLP2(cc-1)+MLP1(cc) per phase ----
  f32x4 macc[3][4];
  #pragma unroll
  for (int a = 0; a < 3; ++a)
    #pragma unroll
    for (int b = 0; b < 4; ++b) macc[a][b] = f32x4{0.f,0.f,0.f,0.f};

  auto mlp1 = [&](int cc, unsigned short* hb) {
    int tile = cc * 8 + wv;
    int n = cc * 128 + wv * 16 + cl;
    f32x4 e0{0,0,0,0}, e1{0,0,0,0}, e2{0,0,0,0}, e3{0,0,0,0};
    short8 bw_c = loadW<WBF>(w1, tile, 48, 0, l, n, 384, kg*8);
    #pragma unroll
    for (int kt = 0; kt < 12; ++kt) {
      short8 bw_n;
      if (kt < 11)
        bw_n = loadW<WBF>(w1, tile, 48, (kt+1)*4, l, n, 384, (kt+1)*32 + kg*8);
      int k0 = kt * 32 + kg * 8;
      short8 a0 = *(const short8*)&aln[(cl     ) * ALN_STR + k0];
      short8 a1 = *(const short8*)&aln[(cl + 16) * ALN_STR + k0];
      short8 a2 = *(const short8*)&aln[(cl + 32) * ALN_STR + k0];
      short8 a3 = *(const short8*)&aln[(cl + 48) * ALN_STR + k0];
      e0 = MFMA_B16(a0, bw_c, e0);
      e1 = MFMA_B16(a1, bw_c, e1);
      e2 = MFMA_B16(a2, bw_c, e2);
      e3 = MFMA_B16(a3, bw_c, e3);
      bw_c = bw_n;
    }
    float bb = b1[n];
    #pragma unroll
    for (int ri = 0; ri < 4; ++ri) {
      f32x4 ee = (ri == 0) ? e0 : (ri == 1) ? e1 : (ri == 2) ? e2 : e3;
      #pragma unroll
      for (int rg = 0; rg < 4; ++rg) {
        int row = kg*4 + rg + 16*ri;
        if (row < 49) {
          float x = ee[rg] + bb;
          // gelu(x) ~= x * sigmoid(1.5957691(x + 0.044715 x^3))
          float t2 = 0.044715f * x * x;
          float arg = __builtin_fmaf(t2, x, x);
          float e = __expf(1.5957691216f * arg);
          float gl = x * (e / (e + 1.f));
          hb[row * HID_STR + wv*16 + cl] = f2bfu(gl);
        }
      }
    }
  };
  auto mlp2 = [&](int cc, const unsigned short* hb) {
    short8 c0_c = loadW<WBF>(w2, wv*3+0, 192, cc*16, l, (wv*3+0)*16+cl, 1536, cc*128 + kg*8);
    short8 c1_c = loadW<WBF>(w2, wv*3+1, 192, cc*16, l, (wv*3+1)*16+cl, 1536, cc*128 + kg*8);
    short8 c2_c = loadW<WBF>(w2, wv*3+2, 192, cc*16, l, (wv*3+2)*16+cl, 1536, cc*128 + kg*8);
    #pragma unroll
    for (int kt = 0; kt < 4; ++kt) {
      short8 c0_n, c1_n, c2_n;
      if (kt < 3) {
        int kcb = cc*16 + (kt+1)*4, k1 = cc*128 + (kt+1)*32 + kg*8;
        c0_n = loadW<WBF>(w2, wv*3+0, 192, kcb, l, (wv*3+0)*16+cl, 1536, k1);
        c1_n = loadW<WBF>(w2, wv*3+1, 192, kcb, l, (wv*3+1)*16+cl, 1536, k1);
        c2_n = loadW<WBF>(w2, wv*3+2, 192, kcb, l, (wv*3+2)*16+cl, 1536, k1);
      }
      int k0 = kt * 32 + kg * 8;
      short8 h0_ = *(const short8*)&hb[(cl     ) * HID_STR + k0];
      short8 h1_ = *(const short8*)&hb[(cl + 16) * HID_STR + k0];
      short8 h2_ = *(const short8*)&hb[(cl + 32) * HID_STR + k0];
      short8 h3_ = *(const short8*)&hb[(cl + 48) * HID_STR + k0];
      macc[0][0] = MFMA_B16(h0_, c0_c, macc[0][0]);
      macc[0][1] = MFMA_B16(h1_, c0_c, macc[0][1]);
      macc[0][2] = MFMA_B16(h2_, c0_c, macc[0][2]);
      macc[0][3] = MFMA_B16(h3_, c0_c, macc[0][3]);
      macc[1][0] = MFMA_B16(h0_, c1_c, macc[1][0]);
      macc[1][1] = MFMA_B16(h1_, c1_c, macc[1][1]);
      macc[1][2] = MFMA_B16(h2_, c1_c, macc[1][2]);
      macc[1][3] = MFMA_B16(h3_, c1_c, macc[1][3]);
      macc[2][0] = MFMA_B16(h0_, c2_c, macc[2][0]);
      macc[2][1] = MFMA_B16(h1_, c2_c, macc[2][1]);
      macc[2][2] = MFMA_B16(h2_, c2_c, macc[2][2]);
      macc[2][3] = MFMA_B16(h3_, c2_c, macc[2][3]);
      c0_c = c0_n; c1_c = c1_n; c2_c = c2_n;
    }
  };

  mlp1(0, hid0);
  __syncthreads();
  for (int cc = 1; cc < 12; ++cc) {
    mlp2(cc - 1, ((cc - 1) & 1) ? hid1 : hid0);
    mlp1(cc, (cc & 1) ? hid1 : hid0);
    __syncthreads();
  }
  mlp2(11, hid1);

  // ---- final: out += mlp + b2 ----
  #pragma unroll
  for (int cii = 0; cii < 3; ++cii) {
    int col = (wv*3 + cii) * 16 + cl;
    float bb2 = b2[col];
    #pragma unroll
    for (int ri = 0; ri < 4; ++ri) {
      #pragma unroll
      for (int rg = 0; rg < 4; ++rg) {
        int row = kg*4 + rg + 16*ri;
        if (row < 49) {
          size_t g = gidx(row, col);
          out[g] = out[g] + macc[cii][ri][rg] + bb2;
        }
      }
    }
  }
}

// ws layout (bf16 elements): ipw[442368] | outw[147456] | w1[589824] | w2[589824]
#define WS_IPW  0
#define WS_OUTW 442368
#define WS_W1   589824
#define WS_W2   1179648
#define WS_TOT  1769472

extern "C" void kernel_launch(void* const* d_in, const int* in_sizes, int n_in,
                              void* d_out, int out_size, void* d_ws, size_t ws_size,
                              hipStream_t stream) {
  (void)in_sizes; (void)n_in; (void)out_size;
  const float* tokens = (const float*)d_in[0];
  const float* ipw  = (const float*)d_in[1];
  const float* ipb  = (const float*)d_in[2];
  const float* outw = (const float*)d_in[3];
  const float* outb = (const float*)d_in[4];
  const float* ln1g = (const float*)d_in[5];
  const float* ln1b = (const float*)d_in[6];
  const float* w1   = (const float*)d_in[7];
  const float* b1   = (const float*)d_in[8];
  const float* w2   = (const float*)d_in[9];
  const float* b2   = (const float*)d_in[10];
  const float* ln2g = (const float*)d_in[11];
  const float* ln2b = (const float*)d_in[12];
  float* out = (float*)d_out;

  bool wbf = (ws_size >= (size_t)WS_TOT * 2);
  if (wbf) {
    unsigned short* wsp = (unsigned short*)d_ws;
    hipLaunchKernelGGL(cvt_pack, dim3((442368+511)/512), dim3(512), 0, stream, ipw,  wsp + WS_IPW,  384,  442368);
    hipLaunchKernelGGL(cvt_pack, dim3((147456+511)/512), dim3(512), 0, stream, outw, wsp + WS_OUTW, 384,  147456);
    hipLaunchKernelGGL(cvt_pack, dim3((589824+511)/512), dim3(512), 0, stream, w1,   wsp + WS_W1,   384,  589824);
    hipLaunchKernelGGL(cvt_pack, dim3((589824+511)/512), dim3(512), 0, stream, w2,   wsp + WS_W2,   1536, 589824);
    (void)hipFuncSetAttribute((const void*)swin_mfma<true>,
                              hipFuncAttributeMaxDynamicSharedMemorySize, SMEM_BYTES);
    hipLaunchKernelGGL((swin_mfma<true>), dim3(512), dim3(1024), SMEM_BYTES, stream,
                       tokens, (const void*)(wsp + WS_IPW), ipb,
                       (const void*)(wsp + WS_OUTW), outb, ln1g, ln1b,
                       (const void*)(wsp + WS_W1), b1, (const void*)(wsp + WS_W2), b2,
                       ln2g, ln2b, out);
  } else {
    (void)hipFuncSetAttribute((const void*)swin_mfma<false>,
                              hipFuncAttributeMaxDynamicSharedMemorySize, SMEM_BYTES);
    hipLaunchKernelGGL((swin_mfma<false>), dim3(512), dim3(1024), SMEM_BYTES, stream,
                       tokens, (const void*)ipw, ipb, (const void*)outw, outb, ln1g, ln1b,
                       (const void*)w1, b1, (const void*)w2, b2, ln2g, ln2b, out);
  }
}